// Round 2
// baseline (231.944 us; speedup 1.0000x reference)
//
#include <hip/hip_runtime.h>

// CTC batch cost (keras ctc_batch_cost semantics), forward only.
// B=512, T=512, C=128 (blank=127), L=32, S=65.
// One wave per batch element; lane s holds alpha[s]; lane 63 also carries
// state 64. Probability domain, 4-row composed updates, exact-pow2 rescale.
//
// Coalesced async row-streaming into a 16-slot LDS ring
// (global_load_lds_dwordx4, 2 instr = 1 group = 4 rows = 2 KiB); per-lane
// q[cls] gathered from LDS. Counted s_waitcnt vmcnt(28) keeps 14 groups
// (28 KiB) in flight per wave. Rescale cadence: ONCE PER GROUP (4 rows) —
// the pair-cadence variant lost denormal bits and failed absmax (6.0>4.64).

#define EPSF 1e-7f

constexpr int T_   = 512;
constexpr int C_   = 128;
constexpr int L_   = 32;
constexpr int NG   = 127;   // groups of 4 rows: rows 1..508
constexpr int NLD  = 17;    // gathered values per group
constexpr int NBUF = 16;    // LDS ring slots (1 slot = 4 rows = 2 KiB)

static_assert(NG == 127, "");

__device__ __forceinline__ void gl16(const float* gp, float* lp) {
    // Each lane copies 16B from its own global address to
    // (wave-uniform LDS base) + lane*16.
    __builtin_amdgcn_global_load_lds(
        (const __attribute__((address_space(1))) void*)gp,
        (__attribute__((address_space(3))) void*)lp,
        16, 0, 0);
}

__launch_bounds__(64)
__global__ void ctc_loss_kernel(const int* __restrict__ y_true,
                                const float* __restrict__ y_pred,
                                float* __restrict__ out) {
    __shared__ float smem[NBUF * 512];   // 32 KiB ring: slot g&15 = rows 1+4g..4+4g

    const int b    = blockIdx.x;
    const int lane = threadIdx.x;

    const float* bb  = y_pred + (size_t)b * T_ * C_;
    const int*   lbl = y_true + b * L_;

    // Static per-lane tables: class and skip-flag for states s-0..s-6, and
    // 0/1 masks for out-of-range shuffle results.
    int   cls[7];
    float sg[7];
#pragma unroll
    for (int i = 0; i < 7; ++i) {
        const int v = lane - i;
        int   c = C_ - 1;     // blank for even / invalid states
        float s = 0.f;
        if (v >= 1 && (v & 1)) {
            c = lbl[(v - 1) >> 1];
            if (v >= 3 && c != lbl[((v - 1) >> 1) - 1]) s = 1.f;
        }
        cls[i] = c;
        sg[i]  = s;
    }
    float msk[9];
#pragma unroll
    for (int i = 0; i < 9; ++i) msk[i] = (lane >= i) ? 1.f : 0.f;

    // t=0 init (prob domain): states 0,1 = q0[cls]+eps, rest 0.
    float a       = (lane < 2) ? (bb[cls[0]] + EPSF) : 0.f;
    float a64     = 0.f;   // state 64, meaningful on lane 63 only
    int   e_total = 0;     // accumulated log2 scale (exact integer)

    // ---- async staging: coalesced rows -> LDS ring -------------------------
    auto issueG = [&](int g) {
        const float* src = bb + (size_t)(1 + 4 * g) * C_ + lane * 4;
        float* dst = &smem[(g & (NBUF - 1)) * 512];
        gl16(src,       dst);         // rows r0,r1 (1 KiB)
        gl16(src + 256, dst + 256);   // rows r2,r3 (1 KiB)
    };

    // LDS gather of the 17 per-lane q values for one group.
    auto ldsq = [&](float (&Qk)[NLD], int g) {
        const float* r = &smem[(g & (NBUF - 1)) * 512];
        Qk[0]  = r[cls[0]];          Qk[1]  = r[cls[1]];
        Qk[2]  = r[cls[2]];          Qk[3]  = r[cls[3]];
        Qk[4]  = r[cls[4]];          Qk[5]  = r[cls[5]];
        Qk[6]  = r[cls[6]];
        Qk[7]  = r[C_ + cls[0]];     Qk[8]  = r[C_ + cls[1]];
        Qk[9]  = r[C_ + cls[2]];     Qk[10] = r[C_ + cls[3]];
        Qk[11] = r[C_ + cls[4]];
        Qk[12] = r[2 * C_ + cls[0]]; Qk[13] = r[2 * C_ + cls[1]];
        Qk[14] = r[2 * C_ + cls[2]];
        Qk[15] = r[3 * C_ + cls[0]]; Qk[16] = r[3 * C_ + cls[1]];
    };

    // Strided wave samples of `a` (lanes 3,7,...,63) for the next rescale.
    float smp[16];
    auto sample = [&]() {
#pragma unroll
        for (int i = 0; i < 16; ++i) smp[i] = __shfl(a, 4 * i + 3);
    };

    // Composed 4-step update (linear in alpha -> scaling commutes).
    auto group4 = [&](float (&Qk)[NLD]) {
        float A[9];
        A[0] = a;
#pragma unroll
        for (int i = 1; i <= 8; ++i) A[i] = __shfl_up(a, i) * msk[i];

        float B[7];
#pragma unroll
        for (int i = 0; i <= 6; ++i)
            B[i] = (A[i] + A[i + 1] + sg[i] * A[i + 2]) * (Qk[i] + EPSF);
        float Cc[5];
#pragma unroll
        for (int i = 0; i <= 4; ++i)
            Cc[i] = (B[i] + B[i + 1] + sg[i] * B[i + 2]) * (Qk[7 + i] + EPSF);
        float D[3];
#pragma unroll
        for (int i = 0; i <= 2; ++i)
            D[i] = (Cc[i] + Cc[i + 1] + sg[i] * Cc[i + 2]) * (Qk[12 + i] + EPSF);

        // state-64 chain (valid on lane 63; harmless elsewhere)
        float z = a64;
        z = (z + A[0])  * (Qk[1]  + EPSF);
        z = (z + B[0])  * (Qk[8]  + EPSF);
        z = (z + Cc[0]) * (Qk[13] + EPSF);
        z = (z + D[0])  * (Qk[16] + EPSF);
        a64 = z;

        a = (D[0] + D[1] + sg[0] * D[2]) * (Qk[15] + EPSF);
    };

    // Exact pow2 rescale from the previously-issued samples.
    auto apply_scale = [&]() {
        float t[8];
#pragma unroll
        for (int i = 0; i < 8; ++i) t[i] = fmaxf(smp[i], smp[i + 8]);
#pragma unroll
        for (int i = 0; i < 4; ++i) t[i] = fmaxf(t[i], t[i + 4]);
        float m = fmaxf(fmaxf(t[0], t[1]), fmaxf(t[2], t[3]));
        m = fmaxf(m, 1e-30f);                 // dead-sample guard (self-corrects)
        const unsigned eb = __float_as_uint(m) >> 23;   // biased exponent
        e_total += (int)eb - 127;
        const float inv = __uint_as_float((254u - eb) << 23);  // 2^-e, exact
        a *= inv;
        a64 *= inv;
    };

    sample();   // seed samples from t=0 alpha

    // Prologue: fill 15 slots (30 global_load_lds in flight), then ensure
    // group 0 has landed (in-order vmcnt retirement: waiting to <=28
    // completes the 2 oldest).
#pragma unroll
    for (int k = 0; k < 15; ++k) issueG(k);
    asm volatile("s_waitcnt vmcnt(28)" ::: "memory");

    float QA[NLD], QB[NLD];
    ldsq(QA, 0);

    // Main loop: pairs of groups (register double-buffer QA/QB). Per group:
    // issue group g+15, wait until pending <= 28 (in-order => group g+1
    // resident in LDS), LDS-prefetch g+1 into the other buffer, compute
    // group g, rescale (baseline per-group cadence: numerics-proven).
    for (int g0 = 0; g0 < 112; g0 += 2) {
        issueG(g0 + 15);
        asm volatile("s_waitcnt vmcnt(28)" ::: "memory");
        ldsq(QB, g0 + 1);
        group4(QA);
        apply_scale();
        sample();

        issueG(g0 + 16);
        asm volatile("s_waitcnt vmcnt(28)" ::: "memory");
        ldsq(QA, g0 + 2);
        group4(QB);
        apply_scale();
        sample();
    }
    // Groups 0..111 computed; QA holds group 112; groups 112..126 issued.

    // Tail-row gathers (rows 509..511) — issued now, drained below.
    float qo[3], qb2[3];
#pragma unroll
    for (int r = 0; r < 3; ++r) {
        const float* rp = bb + (size_t)(509 + r) * C_;
        qo[r]  = rp[cls[0]];
        qb2[r] = rp[cls[1]];
    }

    // Drain everything: groups 112..126 + tail rows all resident after this.
    asm volatile("s_waitcnt vmcnt(0)" ::: "memory");

    // Groups 112..125 (LDS-resident, no vmcnt needed), then group 126.
    for (int g0 = 112; g0 < 126; g0 += 2) {
        ldsq(QB, g0 + 1);
        group4(QA);
        apply_scale();
        sample();
        ldsq(QA, g0 + 2);
        group4(QB);
        apply_scale();
        sample();
    }
    group4(QA);          // group 126 -> alpha after row 508
    apply_scale();

    // Rows 509..511, single steps (3 rows: no rescale needed).
#pragma unroll
    for (int r = 0; r < 3; ++r) {
        float prev = __shfl_up(a, 1) * msk[1];
        float sk   = __shfl_up(a, 2) * msk[2];
        const float anew = (a + prev + sg[0] * sk) * (qo[r] + EPSF);
        a64 = (a64 + a) * (qb2[r] + EPSF);
        a = anew;
    }

    if (lane == 63) {
        out[b] = -(__logf(a + a64) + (float)e_total * 0.6931471805599453f);
    }
}

extern "C" void kernel_launch(void* const* d_in, const int* in_sizes, int n_in,
                              void* d_out, int out_size, void* d_ws, size_t ws_size,
                              hipStream_t stream) {
    const int*   y_true = (const int*)d_in[0];
    const float* y_pred = (const float*)d_in[1];
    float*       out    = (float*)d_out;

    const int B = out_size;   // output is [B,1]
    ctc_loss_kernel<<<B, 64, 0, stream>>>(y_true, y_pred, out);
}

// Round 3
// 197.997 us; speedup vs baseline: 1.1714x; 1.1714x over previous
//
#include <hip/hip_runtime.h>

// CTC batch cost (keras ctc_batch_cost semantics), forward only.
// B=512, T=512, C=128 (blank=127), L=32, S=65.
// One wave per batch element; lane s holds alpha[s]; lane 63 also carries
// state 64. Probability domain, 4-row composed updates, exact-pow2 rescale.
//
// Round-3 change: remove ALL cross-lane LDS-pipe traffic.
//  - alpha shifts: chained v_mov_b32 DPP wave_shr:1 (bound_ctrl zero-fill)
//    instead of 8 ds_bpermute + mask muls per group.
//  - rescale sampling: 16 v_readlane + scalar int-max of float bit patterns
//    (exponent-of-max == max-of-exponents for positive floats) instead of
//    16 ds_bpermute + VALU fmax tree. Bit-identical numerics to baseline.
// Remaining LDS ops: the 17 gather ds_reads per group, prefetched one full
// group ahead (latency covered by VALU issue). Streaming via LDS ring +
// global_load_lds (2 x 1KiB per group) with counted vmcnt(28).

#define EPSF 1e-7f

constexpr int T_   = 512;
constexpr int C_   = 128;
constexpr int L_   = 32;
constexpr int NG   = 127;   // groups of 4 rows: rows 1..508
constexpr int NLD  = 17;    // gathered values per group
constexpr int NBUF = 16;    // LDS ring slots (1 slot = 4 rows = 2 KiB)

static_assert(NG == 127, "");

__device__ __forceinline__ void gl16(const float* gp, float* lp) {
    // Each lane copies 16B from its own global address to
    // (wave-uniform LDS base) + lane*16.
    __builtin_amdgcn_global_load_lds(
        (const __attribute__((address_space(1))) void*)gp,
        (__attribute__((address_space(3))) void*)lp,
        16, 0, 0);
}

// lane j -> value of lane j-1; lane 0 -> 0.  (DPP wave_shr:1, bound_ctrl=0-fill)
__device__ __forceinline__ float wshr1(float x) {
    return __int_as_float(
        __builtin_amdgcn_mov_dpp(__float_as_int(x), 0x138, 0xf, 0xf, true));
}

__launch_bounds__(64)
__global__ void ctc_loss_kernel(const int* __restrict__ y_true,
                                const float* __restrict__ y_pred,
                                float* __restrict__ out) {
    __shared__ float smem[NBUF * 512];   // 32 KiB ring: slot g&15 = rows 1+4g..4+4g

    const int b    = blockIdx.x;
    const int lane = threadIdx.x;

    const float* bb  = y_pred + (size_t)b * T_ * C_;
    const int*   lbl = y_true + b * L_;

    // Static per-lane tables: class and skip-flag for states s-0..s-6.
    int   cls[7];
    float sg[7];
#pragma unroll
    for (int i = 0; i < 7; ++i) {
        const int v = lane - i;
        int   c = C_ - 1;     // blank for even / invalid states
        float s = 0.f;
        if (v >= 1 && (v & 1)) {
            c = lbl[(v - 1) >> 1];
            if (v >= 3 && c != lbl[((v - 1) >> 1) - 1]) s = 1.f;
        }
        cls[i] = c;
        sg[i]  = s;
    }

    // t=0 init (prob domain): states 0,1 = q0[cls]+eps, rest 0.
    float a       = (lane < 2) ? (bb[cls[0]] + EPSF) : 0.f;
    float a64     = 0.f;   // state 64, meaningful on lane 63 only
    int   e_total = 0;     // accumulated log2 scale (exact integer)

    // ---- async staging: coalesced rows -> LDS ring -------------------------
    auto issueG = [&](int g) {
        const float* src = bb + (size_t)(1 + 4 * g) * C_ + lane * 4;
        float* dst = &smem[(g & (NBUF - 1)) * 512];
        gl16(src,       dst);         // rows r0,r1 (1 KiB)
        gl16(src + 256, dst + 256);   // rows r2,r3 (1 KiB)
    };

    // LDS gather of the 17 per-lane q values for one group.
    auto ldsq = [&](float (&Qk)[NLD], int g) {
        const float* r = &smem[(g & (NBUF - 1)) * 512];
        Qk[0]  = r[cls[0]];          Qk[1]  = r[cls[1]];
        Qk[2]  = r[cls[2]];          Qk[3]  = r[cls[3]];
        Qk[4]  = r[cls[4]];          Qk[5]  = r[cls[5]];
        Qk[6]  = r[cls[6]];
        Qk[7]  = r[C_ + cls[0]];     Qk[8]  = r[C_ + cls[1]];
        Qk[9]  = r[C_ + cls[2]];     Qk[10] = r[C_ + cls[3]];
        Qk[11] = r[C_ + cls[4]];
        Qk[12] = r[2 * C_ + cls[0]]; Qk[13] = r[2 * C_ + cls[1]];
        Qk[14] = r[2 * C_ + cls[2]];
        Qk[15] = r[3 * C_ + cls[0]]; Qk[16] = r[3 * C_ + cls[1]];
    };

    // Exponent sample of `a` at lanes 3,7,...,63 (same lanes as baseline's
    // shuffle sample). Positive floats: int-max of bit patterns == bit
    // pattern of float max, and only the exponent is consumed -> max of
    // exponents. 27 = biased exponent of the 1e-30 dead-sample guard.
    auto sample_eb = [&]() -> int {
        int mb = __builtin_amdgcn_readlane(__float_as_int(a), 3);
#pragma unroll
        for (int i = 1; i < 16; ++i) {
            const int v = __builtin_amdgcn_readlane(__float_as_int(a), 4 * i + 3);
            mb = (v > mb) ? v : mb;
        }
        const int eb = (int)((unsigned)mb >> 23);
        return (eb > 27) ? eb : 27;
    };

    // Exact pow2 rescale from a previously-sampled exponent.
    auto apply_scale = [&](int eb) {
        e_total += eb - 127;
        const float inv = __uint_as_float((unsigned)(254 - eb) << 23);  // 2^-e
        a   *= inv;
        a64 *= inv;
    };

    // Composed 4-step update (linear in alpha -> scaling commutes).
    // Shifts via chained DPP wave_shr:1 (zeros fill from lane 0).
    auto group4 = [&](float (&Qk)[NLD]) {
        float A[9];
        A[0] = a;
#pragma unroll
        for (int i = 1; i <= 8; ++i) A[i] = wshr1(A[i - 1]);

        float B[7];
#pragma unroll
        for (int i = 0; i <= 6; ++i)
            B[i] = (A[i] + A[i + 1] + sg[i] * A[i + 2]) * (Qk[i] + EPSF);
        float Cc[5];
#pragma unroll
        for (int i = 0; i <= 4; ++i)
            Cc[i] = (B[i] + B[i + 1] + sg[i] * B[i + 2]) * (Qk[7 + i] + EPSF);
        float D[3];
#pragma unroll
        for (int i = 0; i <= 2; ++i)
            D[i] = (Cc[i] + Cc[i + 1] + sg[i] * Cc[i + 2]) * (Qk[12 + i] + EPSF);

        // state-64 chain (valid on lane 63; harmless elsewhere)
        float z = a64;
        z = (z + A[0])  * (Qk[1]  + EPSF);
        z = (z + B[0])  * (Qk[8]  + EPSF);
        z = (z + Cc[0]) * (Qk[13] + EPSF);
        z = (z + D[0])  * (Qk[16] + EPSF);
        a64 = z;

        a = (D[0] + D[1] + sg[0] * D[2]) * (Qk[15] + EPSF);
    };

    int ebp = sample_eb();   // seed from t=0 alpha (baseline: all samples 0 -> 27)

    // Prologue: fill 15 slots (30 global_load_lds in flight), then ensure
    // group 0 has landed (in-order vmcnt retirement: waiting to <=28
    // completes the 2 oldest).
#pragma unroll
    for (int k = 0; k < 15; ++k) issueG(k);
    asm volatile("s_waitcnt vmcnt(28)" ::: "memory");

    float QA[NLD], QB[NLD];
    ldsq(QA, 0);

    // Main loop: pairs of groups (register double-buffer QA/QB). Per group:
    // issue group g+15, wait until pending <= 28 (in-order => group g+1
    // resident in LDS), LDS-prefetch g+1 into the other buffer, compute
    // group g, rescale (per-group cadence: numerics-proven).
    for (int g0 = 0; g0 < 112; g0 += 2) {
        issueG(g0 + 15);
        asm volatile("s_waitcnt vmcnt(28)" ::: "memory");
        ldsq(QB, g0 + 1);
        group4(QA);
        apply_scale(ebp);
        ebp = sample_eb();

        issueG(g0 + 16);
        asm volatile("s_waitcnt vmcnt(28)" ::: "memory");
        ldsq(QA, g0 + 2);
        group4(QB);
        apply_scale(ebp);
        ebp = sample_eb();
    }
    // Groups 0..111 computed; QA holds group 112; groups 112..126 issued.

    // Tail-row gathers (rows 509..511) — issued now, drained below.
    float qo[3], qb2[3];
#pragma unroll
    for (int r = 0; r < 3; ++r) {
        const float* rp = bb + (size_t)(509 + r) * C_;
        qo[r]  = rp[cls[0]];
        qb2[r] = rp[cls[1]];
    }

    // Drain everything: groups 112..126 + tail rows all resident after this.
    asm volatile("s_waitcnt vmcnt(0)" ::: "memory");

    // Groups 112..125 (LDS-resident), then group 126.
    for (int g0 = 112; g0 < 126; g0 += 2) {
        ldsq(QB, g0 + 1);
        group4(QA);
        apply_scale(ebp);
        ebp = sample_eb();
        ldsq(QA, g0 + 2);
        group4(QB);
        apply_scale(ebp);
        ebp = sample_eb();
    }
    group4(QA);          // group 126 -> alpha after row 508
    apply_scale(ebp);

    // Rows 509..511, single steps (3 rows: no rescale needed).
#pragma unroll
    for (int r = 0; r < 3; ++r) {
        const float p1 = wshr1(a);
        const float p2 = wshr1(p1);
        const float anew = (a + p1 + sg[0] * p2) * (qo[r] + EPSF);
        a64 = (a64 + a) * (qb2[r] + EPSF);
        a = anew;
    }

    if (lane == 63) {
        out[b] = -(__logf(a + a64) + (float)e_total * 0.6931471805599453f);
    }
}

extern "C" void kernel_launch(void* const* d_in, const int* in_sizes, int n_in,
                              void* d_out, int out_size, void* d_ws, size_t ws_size,
                              hipStream_t stream) {
    const int*   y_true = (const int*)d_in[0];
    const float* y_pred = (const float*)d_in[1];
    float*       out    = (float*)d_out;

    const int B = out_size;   // output is [B,1]
    ctc_loss_kernel<<<B, 64, 0, stream>>>(y_true, y_pred, out);
}